// Round 1
// baseline (192.768 us; speedup 1.0000x reference)
//
#include <hip/hip_runtime.h>
#include <hip/hip_bf16.h>

// Problem: B=32, S=2048, D=512, FULL=60000.
// vals[b,s] = dot(h[b,s,:], w) + bias;  out[b, gene_pos[b,s]] = vals  (pos<FULL)
// Memory-bound: 134 MB read of h dominates. One wave64 per token, float4 loads.

#define B_DIM 32
#define S_DIM 2048
#define D_DIM 512
#define FULL_LEN 60000

__global__ __launch_bounds__(256) void conv_scatter_kernel(
        const float* __restrict__ h,
        const int* __restrict__ gene_pos,
        const float* __restrict__ w,
        const float* __restrict__ bias,
        float* __restrict__ out) {
    const int wave = threadIdx.x >> 6;               // 0..3 (4 waves/block)
    const int lane = threadIdx.x & 63;
    const int token = (blockIdx.x << 2) + wave;      // 0 .. B*S-1
    // token < B*S guaranteed by exact grid sizing (65536 tokens / 4 per block)

    const int brow = token >> 11;                    // token / S_DIM
    const float4* hp = (const float4*)(h + (size_t)token * D_DIM);
    const float4* wp = (const float4*)w;

    // lane i covers elements [8i, 8i+8): two float4 each from h and w
    const int v = lane << 1;
    float4 a0 = hp[v];
    float4 a1 = hp[v + 1];
    float4 w0 = wp[v];
    float4 w1 = wp[v + 1];

    float sum = a0.x * w0.x + a0.y * w0.y + a0.z * w0.z + a0.w * w0.w
              + a1.x * w1.x + a1.y * w1.y + a1.z * w1.z + a1.w * w1.w;

    // wave64 butterfly reduction
    #pragma unroll
    for (int off = 32; off > 0; off >>= 1)
        sum += __shfl_xor(sum, off, 64);

    if (lane == 0) {
        const int pos = gene_pos[token];
        if (pos < FULL_LEN) {
            out[(size_t)brow * FULL_LEN + pos] = sum + bias[0];
        }
    }
}

extern "C" void kernel_launch(void* const* d_in, const int* in_sizes, int n_in,
                              void* d_out, int out_size, void* d_ws, size_t ws_size,
                              hipStream_t stream) {
    const float* h        = (const float*)d_in[0];
    const int*   gene_pos = (const int*)d_in[1];
    const float* w        = (const float*)d_in[2];
    const float* bias     = (const float*)d_in[3];
    float* out = (float*)d_out;

    // d_out is re-poisoned to 0xAA before every timed launch: zero it.
    hipMemsetAsync(out, 0, (size_t)out_size * sizeof(float), stream);

    const int tokens = B_DIM * S_DIM;                // 65536
    const int blocks = tokens / 4;                   // 4 tokens (waves) per block
    conv_scatter_kernel<<<blocks, 256, 0, stream>>>(h, gene_pos, w, bias, out);
}